// Round 5
// baseline (12.467 us; speedup 1.0000x reference)
//
#include <hip/hip_runtime.h>
#include <hip/hip_bf16.h>

// CentersDistance: logits[c][q] = -||c-q||^2 = 2*dot(c,q) - ||c||^2 - ||q||^2
// inputs: [4096][128] f32, centers: [256][128] f32, out: [256][4096] f32
//
// v5 = v4 (fused norms, no LDS/barriers, 64x64 tile / 4 waves / 256 blocks)
// with swapped MFMA operands: A<-inputs(q), B<-centers(c) so D[q][c] gives
// each lane 4 CONSECUTIVE q outputs -> float4 nontemporal stores, and the
// c-norm is lane-local in the epilogue (c_loc == lr).

typedef __attribute__((ext_vector_type(8))) short short8;  // 8 bf16
typedef __attribute__((ext_vector_type(4))) float f32x4;

constexpr int QN = 4096;
constexpr int CN = 256;
constexpr int DK = 128;

static __device__ inline short f2bf(float x) {
    __hip_bfloat16 h = __float2bfloat16(x);   // RNE; pairs fold to v_cvt_pk
    return __builtin_bit_cast(short, h);
}

__global__ __launch_bounds__(256) void centers_dist_v5(
    const float* __restrict__ inputs,
    const float* __restrict__ centers,
    float* __restrict__ out)
{
    const int tid  = threadIdx.x;
    const int lane = tid & 63;
    const int wid  = tid >> 6;        // 0..3
    const int wr   = wid >> 1;        // c-half of the 64x64 tile
    const int wc   = wid & 1;         // q-half
    const int c0   = blockIdx.x * 64;
    const int q0   = blockIdx.y * 64;
    const int lr   = lane & 15;       // fragment row
    const int lg   = lane >> 4;       // k-group 0..3
    const int lk   = lg * 8;          // 8 consecutive k per lane

    // A-operand = inputs (q rows), B-operand = centers (c rows)
    const float* qp0 = &inputs [(q0 + wc * 32 +  0 + lr) * DK + lk];
    const float* qp1 = &inputs [(q0 + wc * 32 + 16 + lr) * DK + lk];
    const float* cp0 = &centers[(c0 + wr * 32 +  0 + lr) * DK + lk];
    const float* cp1 = &centers[(c0 + wr * 32 + 16 + lr) * DK + lk];

    f32x4 acc[2][2] = {};             // acc[fm(q-frag)][fn(c-frag)]
    float qsum[2] = {0.f, 0.f};       // sq-sum partials, q rows (fm*16+lr)
    float csum[2] = {0.f, 0.f};       // sq-sum partials, c rows (fn*16+lr)

    #pragma unroll
    for (int ks = 0; ks < 4; ++ks) {
        const float* qps[2] = {qp0 + ks * 32, qp1 + ks * 32};
        const float* cps[2] = {cp0 + ks * 32, cp1 + ks * 32};
        short8 af[2], bfr[2];
        #pragma unroll
        for (int f = 0; f < 2; ++f) {
            float4 v0 = *reinterpret_cast<const float4*>(qps[f]);
            float4 v1 = *reinterpret_cast<const float4*>(qps[f] + 4);
            qsum[f] += v0.x*v0.x + v0.y*v0.y + v0.z*v0.z + v0.w*v0.w
                     + v1.x*v1.x + v1.y*v1.y + v1.z*v1.z + v1.w*v1.w;
            af[f] = short8{f2bf(v0.x), f2bf(v0.y), f2bf(v0.z), f2bf(v0.w),
                           f2bf(v1.x), f2bf(v1.y), f2bf(v1.z), f2bf(v1.w)};
        }
        #pragma unroll
        for (int f = 0; f < 2; ++f) {
            float4 v0 = *reinterpret_cast<const float4*>(cps[f]);
            float4 v1 = *reinterpret_cast<const float4*>(cps[f] + 4);
            csum[f] += v0.x*v0.x + v0.y*v0.y + v0.z*v0.z + v0.w*v0.w
                     + v1.x*v1.x + v1.y*v1.y + v1.z*v1.z + v1.w*v1.w;
            bfr[f] = short8{f2bf(v0.x), f2bf(v0.y), f2bf(v0.z), f2bf(v0.w),
                            f2bf(v1.x), f2bf(v1.y), f2bf(v1.z), f2bf(v1.w)};
        }
        #pragma unroll
        for (int fm = 0; fm < 2; ++fm)
            #pragma unroll
            for (int fn = 0; fn < 2; ++fn)
                acc[fm][fn] = __builtin_amdgcn_mfma_f32_16x16x32_bf16(
                    af[fm], bfr[fn], acc[fm][fn], 0, 0, 0);
    }

    // Reduce the 4 k-groups: after xor(16)+xor(32) every lane holds the FULL
    // row norm for its lr (both q-side and c-side).
    #pragma unroll
    for (int f = 0; f < 2; ++f) {
        qsum[f] += __shfl_xor(qsum[f], 16);
        qsum[f] += __shfl_xor(qsum[f], 32);
        csum[f] += __shfl_xor(csum[f], 16);
        csum[f] += __shfl_xor(csum[f], 32);
    }

    // D-frag mapping (mirror of verified m89/m91): col = lane&15 = c row of
    // the B operand; row = lg*4+j = q row of the A operand.
    #pragma unroll
    for (int fm = 0; fm < 2; ++fm) {
        float qn[4];
        #pragma unroll
        for (int j = 0; j < 4; ++j)
            qn[j] = __shfl(qsum[fm], lg * 4 + j);   // lane r holds q-row r
        const int q_glob = q0 + wc * 32 + fm * 16 + lg * 4;
        #pragma unroll
        for (int fn = 0; fn < 2; ++fn) {
            const float cn = csum[fn];              // lane-local: c_loc == lr
            const int c_glob = c0 + wr * 32 + fn * 16 + lr;
            f32x4 v;
            #pragma unroll
            for (int j = 0; j < 4; ++j)
                v[j] = fmaf(2.f, acc[fm][fn][j], -(cn + qn[j]));
            __builtin_nontemporal_store(
                v, reinterpret_cast<f32x4*>(&out[c_glob * QN + q_glob]));
        }
    }
}

extern "C" void kernel_launch(void* const* d_in, const int* in_sizes, int n_in,
                              void* d_out, int out_size, void* d_ws, size_t ws_size,
                              hipStream_t stream) {
    const float* inputs  = (const float*)d_in[0];   // [4096][128]
    const float* centers = (const float*)d_in[1];   // [ 256][128]
    float* out = (float*)d_out;                     // [ 256][4096]

    dim3 grid(CN / 64, QN / 64);   // 4 x 64 = 256 blocks, 4 waves each
    centers_dist_v5<<<grid, dim3(256), 0, stream>>>(inputs, centers, out);
}

// Round 6
// 12.260 us; speedup vs baseline: 1.0169x; 1.0169x over previous
//
#include <hip/hip_runtime.h>
#include <hip/hip_bf16.h>

// CentersDistance: logits[c][q] = -||c-q||^2 = 2*dot(c,q) - ||c||^2 - ||q||^2
// inputs: [4096][128] f32, centers: [256][128] f32, out: [256][4096] f32
//
// v6 = v4 (A=centers/B=inputs MFMA, fused in-register norms, no LDS, no
// barriers, coalesced 64B-segment stores) with the q-tile halved:
// 64c x 32q per block, grid 4 x 128 = 512 blocks = 2 blocks/CU = 2 waves/SIMD.
// Clean occupancy test: +50% L2 traffic (16->24 MB, ~0.25 us of L2 pipe)
// vs halved exposed cold-load latency. v3's occupancy test was confounded
// by 4x traffic; this isolates the variable.

typedef __attribute__((ext_vector_type(8))) short short8;  // 8 bf16
typedef __attribute__((ext_vector_type(4))) float f32x4;

constexpr int QN = 4096;
constexpr int CN = 256;
constexpr int DK = 128;

static __device__ inline short f2bf(float x) {
    __hip_bfloat16 h = __float2bfloat16(x);   // RNE; pairs fold to v_cvt_pk
    return __builtin_bit_cast(short, h);
}

__global__ __launch_bounds__(256) void centers_dist_v6(
    const float* __restrict__ inputs,
    const float* __restrict__ centers,
    float* __restrict__ out)
{
    const int tid  = threadIdx.x;
    const int lane = tid & 63;
    const int wid  = tid >> 6;        // 0..3
    const int wr   = wid >> 1;        // c-half (32 rows each)
    const int wc   = wid & 1;         // q-half (16 cols each)
    const int c0   = blockIdx.x * 64;
    const int q0   = blockIdx.y * 32;
    const int lr   = lane & 15;       // fragment row
    const int lg   = lane >> 4;       // k-group 0..3
    const int lk   = lg * 8;          // 8 consecutive k per lane

    // A-operand = centers (c rows, 2 frags), B-operand = inputs (q rows, 1 frag)
    const float* cp0 = &centers[(c0 + wr * 32 +  0 + lr) * DK + lk];
    const float* cp1 = &centers[(c0 + wr * 32 + 16 + lr) * DK + lk];
    const float* qp  = &inputs [(q0 + wc * 16 +      lr) * DK + lk];

    f32x4 acc[2] = {};                // acc[fm], D = 16q x 16c... D[c][q]
    float csum[2] = {0.f, 0.f};       // c-row sq-sum partials (rows fm*16+lr)
    float qsum = 0.f;                 // q-row sq-sum partial  (row lr)

    #pragma unroll
    for (int ks = 0; ks < 4; ++ks) {
        const float* cps[2] = {cp0 + ks * 32, cp1 + ks * 32};
        short8 af[2], bfr;
        #pragma unroll
        for (int f = 0; f < 2; ++f) {
            float4 v0 = *reinterpret_cast<const float4*>(cps[f]);
            float4 v1 = *reinterpret_cast<const float4*>(cps[f] + 4);
            csum[f] += v0.x*v0.x + v0.y*v0.y + v0.z*v0.z + v0.w*v0.w
                     + v1.x*v1.x + v1.y*v1.y + v1.z*v1.z + v1.w*v1.w;
            af[f] = short8{f2bf(v0.x), f2bf(v0.y), f2bf(v0.z), f2bf(v0.w),
                           f2bf(v1.x), f2bf(v1.y), f2bf(v1.z), f2bf(v1.w)};
        }
        {
            float4 v0 = *reinterpret_cast<const float4*>(qp + ks * 32);
            float4 v1 = *reinterpret_cast<const float4*>(qp + ks * 32 + 4);
            qsum += v0.x*v0.x + v0.y*v0.y + v0.z*v0.z + v0.w*v0.w
                  + v1.x*v1.x + v1.y*v1.y + v1.z*v1.z + v1.w*v1.w;
            bfr = short8{f2bf(v0.x), f2bf(v0.y), f2bf(v0.z), f2bf(v0.w),
                         f2bf(v1.x), f2bf(v1.y), f2bf(v1.z), f2bf(v1.w)};
        }
        #pragma unroll
        for (int fm = 0; fm < 2; ++fm)
            acc[fm] = __builtin_amdgcn_mfma_f32_16x16x32_bf16(
                af[fm], bfr, acc[fm], 0, 0, 0);
    }

    // xor over 16,32 sums the 4 k-groups -> every lane holds the FULL norm
    // of its row lr (lanes {l, l^16, l^32, l^48} share lr).
    #pragma unroll
    for (int f = 0; f < 2; ++f) {
        csum[f] += __shfl_xor(csum[f], 16);
        csum[f] += __shfl_xor(csum[f], 32);
    }
    qsum += __shfl_xor(qsum, 16);
    qsum += __shfl_xor(qsum, 32);

    // D-frag mapping (verified m89/m91): col = lane&15 = q (B rows),
    // row = lg*4+j = c (A rows). Stores: 16 lanes x 4B consecutive q = 64B
    // segments, 4 lg-groups on 4 distinct c rows per instruction.
    const int q_glob = q0 + wc * 16 + lr;
    #pragma unroll
    for (int fm = 0; fm < 2; ++fm) {
        #pragma unroll
        for (int j = 0; j < 4; ++j) {
            int r = lg * 4 + j;
            float cn = __shfl(csum[fm], r);          // lane r holds c-row r
            int c_loc = wr * 32 + fm * 16 + r;
            out[(c0 + c_loc) * QN + q_glob] = fmaf(2.f, acc[fm][j], -(cn + qsum));
        }
    }
}

extern "C" void kernel_launch(void* const* d_in, const int* in_sizes, int n_in,
                              void* d_out, int out_size, void* d_ws, size_t ws_size,
                              hipStream_t stream) {
    const float* inputs  = (const float*)d_in[0];   // [4096][128]
    const float* centers = (const float*)d_in[1];   // [ 256][128]
    float* out = (float*)d_out;                     // [ 256][4096]

    dim3 grid(CN / 64, QN / 32);   // 4 x 128 = 512 blocks, 4 waves each
    centers_dist_v6<<<grid, dim3(256), 0, stream>>>(inputs, centers, out);
}

// Round 7
// 10.959 us; speedup vs baseline: 1.1375x; 1.1187x over previous
//
#include <hip/hip_runtime.h>
#include <hip/hip_bf16.h>

// CentersDistance: logits[c][q] = -||c-q||^2 = 2*dot(c,q) - ||c||^2 - ||q||^2
// inputs: [4096][128] f32, centers: [256][128] f32, out: [256][4096] f32
//
// v4 (FINAL): 64x64 tile/block, 4 waves of 32x32, 256 blocks (1/CU).
// Cross-term via mfma_f32_16x16x32_bf16; row norms fused into the fragment
// loads (fp32 square-sum of the same floats, shfl_xor reduce). No LDS, no
// barriers, single pass, 64B-segment coalesced stores.
//
// Ablated alternatives (all slower): LDS-staged fp32 (15.1), 2-pass norms
// (12.5), 4x occupancy/16x16 tiles (14.1), NT col-major stores (12.5),
// 2 blocks/CU 64x32 (12.3). This kernel: 11.39 us, absmax 2.0.
// Total is dominated by the ~10 us dispatch/replay floor; body ~1.4 us vs
// ~1.1 us physical (6.1 MB HBM-touched at 6.3 TB/s + cold-miss ramp).

typedef __attribute__((ext_vector_type(8))) short short8;  // 8 bf16
typedef __attribute__((ext_vector_type(4))) float f32x4;

constexpr int QN = 4096;
constexpr int CN = 256;
constexpr int DK = 128;

static __device__ inline short f2bf(float x) {
    __hip_bfloat16 h = __float2bfloat16(x);   // RNE; pairs fold to v_cvt_pk
    return __builtin_bit_cast(short, h);
}

__global__ __launch_bounds__(256) void centers_dist_v4(
    const float* __restrict__ inputs,
    const float* __restrict__ centers,
    float* __restrict__ out)
{
    const int tid  = threadIdx.x;
    const int lane = tid & 63;
    const int wid  = tid >> 6;        // 0..3
    const int wr   = wid >> 1;        // c-half of the 64x64 tile
    const int wc   = wid & 1;         // q-half
    const int c0   = blockIdx.x * 64;
    const int q0   = blockIdx.y * 64;
    const int lr   = lane & 15;       // fragment row
    const int lg   = lane >> 4;       // k-group 0..3
    const int lk   = lg * 8;          // 8 consecutive k per lane

    const float* cp0 = &centers[(c0 + wr * 32 +  0 + lr) * DK + lk];
    const float* cp1 = &centers[(c0 + wr * 32 + 16 + lr) * DK + lk];
    const float* qp0 = &inputs [(q0 + wc * 32 +  0 + lr) * DK + lk];
    const float* qp1 = &inputs [(q0 + wc * 32 + 16 + lr) * DK + lk];

    f32x4 acc[2][2] = {};
    float csum[2] = {0.f, 0.f};       // sq-sum partials, rows (fm*16+lr)
    float qsum[2] = {0.f, 0.f};

    #pragma unroll
    for (int ks = 0; ks < 4; ++ks) {
        const float* cps[2] = {cp0 + ks * 32, cp1 + ks * 32};
        const float* qps[2] = {qp0 + ks * 32, qp1 + ks * 32};
        short8 af[2], bfr[2];
        #pragma unroll
        for (int f = 0; f < 2; ++f) {
            float4 v0 = *reinterpret_cast<const float4*>(cps[f]);
            float4 v1 = *reinterpret_cast<const float4*>(cps[f] + 4);
            csum[f] += v0.x*v0.x + v0.y*v0.y + v0.z*v0.z + v0.w*v0.w
                     + v1.x*v1.x + v1.y*v1.y + v1.z*v1.z + v1.w*v1.w;
            af[f] = short8{f2bf(v0.x), f2bf(v0.y), f2bf(v0.z), f2bf(v0.w),
                           f2bf(v1.x), f2bf(v1.y), f2bf(v1.z), f2bf(v1.w)};
        }
        #pragma unroll
        for (int f = 0; f < 2; ++f) {
            float4 v0 = *reinterpret_cast<const float4*>(qps[f]);
            float4 v1 = *reinterpret_cast<const float4*>(qps[f] + 4);
            qsum[f] += v0.x*v0.x + v0.y*v0.y + v0.z*v0.z + v0.w*v0.w
                     + v1.x*v1.x + v1.y*v1.y + v1.z*v1.z + v1.w*v1.w;
            bfr[f] = short8{f2bf(v0.x), f2bf(v0.y), f2bf(v0.z), f2bf(v0.w),
                            f2bf(v1.x), f2bf(v1.y), f2bf(v1.z), f2bf(v1.w)};
        }
        #pragma unroll
        for (int fm = 0; fm < 2; ++fm)
            #pragma unroll
            for (int fn = 0; fn < 2; ++fn)
                acc[fm][fn] = __builtin_amdgcn_mfma_f32_16x16x32_bf16(
                    af[fm], bfr[fn], acc[fm][fn], 0, 0, 0);
    }

    // Each lane covered k in {ks*32+lg*8 .. +7}; xor over 16,32 sums the 4
    // lg-groups -> every lane holds the FULL row norm for its lr.
    #pragma unroll
    for (int f = 0; f < 2; ++f) {
        csum[f] += __shfl_xor(csum[f], 16);
        csum[f] += __shfl_xor(csum[f], 32);
        qsum[f] += __shfl_xor(qsum[f], 16);
        qsum[f] += __shfl_xor(qsum[f], 32);
    }

    // D-frag mapping (verified m89/m91): col = lane&15 (q), row = lg*4+j (c).
    // Stores: 16 lanes x 4B consecutive q = 64B segments per instruction.
    #pragma unroll
    for (int fm = 0; fm < 2; ++fm) {
        #pragma unroll
        for (int fn = 0; fn < 2; ++fn) {
            int q_loc = wc * 32 + fn * 16 + lr;
            #pragma unroll
            for (int j = 0; j < 4; ++j) {
                int r = lg * 4 + j;                      // row within 16-frag
                float cn = __shfl(csum[fm], r);          // lane r holds row r
                int c_loc = wr * 32 + fm * 16 + r;
                out[(c0 + c_loc) * QN + (q0 + q_loc)] =
                    fmaf(2.f, acc[fm][fn][j], -(cn + qsum[fn]));
            }
        }
    }
}

extern "C" void kernel_launch(void* const* d_in, const int* in_sizes, int n_in,
                              void* d_out, int out_size, void* d_ws, size_t ws_size,
                              hipStream_t stream) {
    const float* inputs  = (const float*)d_in[0];   // [4096][128]
    const float* centers = (const float*)d_in[1];   // [ 256][128]
    float* out = (float*)d_out;                     // [ 256][4096]

    dim3 grid(CN / 64, QN / 64);   // 4 x 64 = 256 blocks, 4 waves each
    centers_dist_v4<<<grid, dim3(256), 0, stream>>>(inputs, centers, out);
}